// Round 4
// baseline (578.117 us; speedup 1.0000x reference)
//
#include <hip/hip_runtime.h>
#include <math.h>

namespace {
constexpr int D = 256;
constexpr int H = 8;
constexpr int HD = 32;
constexpr int B = 8;
constexpr int S = 127;
constexpr int N = 128;
constexpr float LN_EPS = 1e-5f;

// ws layout (float offsets). P1T/P2T are stored PACKED:
// element (b, c, i) at (b*64 + (c>>2))*512 + i*4 + (c&3)  -> float4 over c for fixed i.
// P1T rows INCLUDE eb1 (folded at kA time).
constexpr int WS_P1T = 0;                  // B*D*N
constexpr int WS_P2T = WS_P1T + B * D * N; // B*D*N
constexpr int WS_V   = WS_P2T + B * D * N; // B*N*D (row-major)
constexpr int WS_AQ  = WS_V + B * N * D;   // B*H*N
constexpr int WS_AK  = WS_AQ + B * H * N;  // B*H*N
constexpr int WS_FQK = WS_AK + B * H * N;  // D*16 (wq-fold | wk-fold)
constexpr int WS_V2  = WS_FQK + D * 16;    // H*D (transposed: [h][c])
constexpr int WS_BF  = WS_V2 + D * H;      // 32 (bq-fold[8], bk-fold[8], be-fold[8])

union F4 { float4 v; float f[4]; };
} // namespace

// K1: fold wq/wk with attn_w[:32]/[32:64] -> FQK (D x 16), ew2 with attn_w[64:96]
// -> V2T (H x D), plus bias folds. Thread-per-output.
__global__ __launch_bounds__(256) void k1_fold(
    const float* __restrict__ wq, const float* __restrict__ wk,
    const float* __restrict__ ew2, const float* __restrict__ bq,
    const float* __restrict__ bk, const float* __restrict__ eb2,
    const float* __restrict__ attn_w, float* __restrict__ ws) {
  float* FQK = ws + WS_FQK;
  float* V2T = ws + WS_V2;
  float* BF  = ws + WS_BF;
  const int tg = blockIdx.x * 256 + threadIdx.x;
  if (tg < 6144) {
    const int mat = tg >> 11;
    const int rem = tg & 2047;
    const int c = rem >> 3;
    const int h = rem & 7;
    const float* W = (mat == 0) ? wq : (mat == 1) ? wk : ew2;
    const float* aw = attn_w + mat * HD;
    const float* wrow = W + c * D + h * HD;
    float s = 0.f;
#pragma unroll
    for (int d = 0; d < HD; ++d) s = fmaf(wrow[d], aw[d], s);
    if (mat < 2) FQK[c * 16 + mat * 8 + h] = s;
    else         V2T[h * D + c] = s;
  } else if (tg < 6168) {
    const int idx = tg - 6144;
    const int mat = idx >> 3;
    const int h = idx & 7;
    const float* bias = (mat == 0) ? bq : (mat == 1) ? bk : eb2;
    const float* aw = attn_w + mat * HD;
    float s = 0.f;
#pragma unroll
    for (int d = 0; d < HD; ++d) s = fmaf(bias[h * HD + d], aw[d], s);
    BF[mat * 8 + h] = s;
  }
}

// KA: merged P-matrices (role 0, blocks 0..255; P1 gets +eb1) and V/aq/ak (role 1).
__global__ __launch_bounds__(256) void kA_pre(
    const float* __restrict__ desc, const float* __restrict__ ew1,
    const float* __restrict__ eb1,
    const float* __restrict__ nv, const float* __restrict__ wv,
    const float* __restrict__ bv, float* __restrict__ ws) {
  const int blk = blockIdx.x;
  const int t = threadIdx.x;
  __shared__ float rows[4][264];
  __shared__ float aqred[4][64];

  if (blk < 256) {
    // ---- role 0: P1 = desc @ ew1[:D] + eb1, P2 = desc @ ew1[D:], packed-transposed
    float* P1Tf = ws + WS_P1T;
    float* P2Tf = ws + WS_P2T;
    const int b = blk >> 5;
    const int i0 = (blk & 31) * 4;
    for (int k = t; k < 4 * D; k += 256) {
      const int r = k >> 8, c = k & (D - 1);
      const int row = i0 + r;
      rows[r][c] = (row < S) ? desc[(b * S + row) * D + c] : 0.f;
    }
    __syncthreads();
    float a1[4], a2[4];
#pragma unroll
    for (int ii = 0; ii < 4; ++ii) { a1[ii] = 0.f; a2[ii] = 0.f; }
    for (int c2 = 0; c2 < D; c2 += 4) {
      float w1[4], w2[4];
#pragma unroll
      for (int e = 0; e < 4; ++e) {
        w1[e] = ew1[(c2 + e) * D + t];
        w2[e] = ew1[(D + c2 + e) * D + t];
      }
#pragma unroll
      for (int ii = 0; ii < 4; ++ii) {
        F4 dv; dv.v = *(const float4*)&rows[ii][c2];
#pragma unroll
        for (int e = 0; e < 4; ++e) {
          a1[ii] = fmaf(dv.f[e], w1[e], a1[ii]);
          a2[ii] = fmaf(dv.f[e], w2[e], a2[ii]);
        }
      }
    }
    const float ebv = eb1[t];
    const int pbase = (b * 64 + (t >> 2)) * 512 + (t & 3);
#pragma unroll
    for (int ii = 0; ii < 4; ++ii) {
      if (i0 + ii < S) {
        P1Tf[pbase + (i0 + ii) * 4] = a1[ii] + ebv;
        P2Tf[pbase + (i0 + ii) * 4] = a2[ii];
      }
    }
  } else {
    // ---- role 1: v = nv @ wv + bv, aq/ak via folded FQK ----
    float* Vf  = ws + WS_V;
    float* AQ  = ws + WS_AQ;
    float* AK  = ws + WS_AK;
    const float* FQK = ws + WS_FQK;
    const float* BF  = ws + WS_BF;
    const int blk2 = blk - 256;
    const int b = blk2 >> 5;
    const int j0 = (blk2 & 31) * 4;
    for (int k = t; k < 4 * D; k += 256) {
      const int r = k >> 8, c = k & (D - 1);
      rows[r][c] = nv[(b * N + j0 + r) * D + c];
    }
    __syncthreads();
    float acc[4];
#pragma unroll
    for (int jj = 0; jj < 4; ++jj) acc[jj] = 0.f;
    for (int c2 = 0; c2 < D; c2 += 4) {
      float wvv[4];
#pragma unroll
      for (int e = 0; e < 4; ++e) wvv[e] = wv[(c2 + e) * D + t];
#pragma unroll
      for (int jj = 0; jj < 4; ++jj) {
        F4 x; x.v = *(const float4*)&rows[jj][c2];
#pragma unroll
        for (int e = 0; e < 4; ++e) acc[jj] = fmaf(x.f[e], wvv[e], acc[jj]);
      }
    }
    const float bias = bv[t];
#pragma unroll
    for (int jj = 0; jj < 4; ++jj)
      Vf[(b * N + j0 + jj) * D + t] = acc[jj] + bias;

    const int pair = t & 63;        // (row il, output oi)
    const int cq = t >> 6;          // channel quarter
    const int il = pair >> 4, oi = pair & 15;
    float s = 0.f;
    for (int c = cq * 64; c < cq * 64 + 64; ++c)
      s = fmaf(rows[il][c], FQK[c * 16 + oi], s);
    aqred[cq][pair] = s;
    __syncthreads();
    if (t < 64) {
      const int il2 = t >> 4, oi2 = t & 15;
      float s2 = aqred[0][t] + aqred[1][t] + aqred[2][t] + aqred[3][t] + BF[oi2];
      if (oi2 < 8) AQ[(b * H + oi2) * N + j0 + il2] = s2;
      else         AK[(b * H + (oi2 - 8)) * N + j0 + il2] = s2;
    }
  }
}

// K4: edge-MLP -> scores -> softmax -> attn write.
// grid 512 (XCD-swizzled): block = (b, 2-row i-tile). 512 threads:
// jl = t&127 (column j), q = t>>7 (channel quarter, 64 channels).
// Each lane holds its P2[jl] 64-channel slice in 16 float4 REGISTERS,
// read once per block -> minimal fabric traffic. p1 row is a broadcast
// LDS read; v2/ln_g/ln_b are uniform global reads (L1-resident).
__global__ __launch_bounds__(512, 4) void k4_attn(
    const float* __restrict__ ws,
    const float* __restrict__ ln_g, const float* __restrict__ ln_b,
    const float* __restrict__ attn_bp, float* __restrict__ attnp) {
  const int bid = blockIdx.x;
  const int wg = (bid & 7) * 64 + (bid >> 3);   // bijective over 512
  const int b = wg >> 6;
  const int i0 = (wg & 63) * 2;
  const int t = threadIdx.x;
  const int jl = t & 127;
  const int q = t >> 7;

  __shared__ float p1e[2][D];
  __shared__ float red1[4][128], red2[4][128];
  __shared__ float dsh[4][128][9];
  __shared__ float aqs[2][8];
  __shared__ float redm[8][2], reds[8][2];

  const float* P1Tf = ws + WS_P1T;
  const float* AQ   = ws + WS_AQ;
  const float* AK   = ws + WS_AK;
  const float* BF   = ws + WS_BF;
  const float* v2p  = ws + WS_V2;

  for (int k = t; k < 2 * D; k += 512) {
    const int r = k >> 8, c = k & 255;
    const int idx = i0 + r - 1;
    p1e[r][c] = (idx >= 0)
        ? P1Tf[(b * 64 + (c >> 2)) * 512 + idx * 4 + (c & 3)] : 0.f;
  }
  if (t < 16) {
    const int r = t >> 3, h = t & 7;
    aqs[r][h] = AQ[(b * H + h) * N + i0 + r] + BF[16 + h] + attn_bp[0];
  }
  float akr[2];
  akr[0] = AK[(b * H + q) * N + jl];
  akr[1] = AK[(b * H + q + 4) * N + jl];
  __syncthreads();

  const int jm1 = (jl == 0) ? 0 : jl - 1;
  const float4* P14 = reinterpret_cast<const float4*>(ws + WS_P1T);
  const float4* P24 = reinterpret_cast<const float4*>(ws + WS_P2T);
  const int base4 = b * 64 * 128;
  const int c4g0 = q * 16;

  // P2 slice -> registers (64 channels)
  F4 pp[16];
#pragma unroll
  for (int c4 = 0; c4 < 16; ++c4)
    pp[c4].v = P24[base4 + (c4g0 + c4) * 128 + jm1];

  const int w = t >> 6;  // wave id; softmax partner is w^1

  for (int r = 0; r < 2; ++r) {
    const int irow = i0 + r;
    const bool row0 = (irow == 0);

    // LN stats over my 64 channels
    float psum = 0.f, psq = 0.f;
#pragma unroll
    for (int c4 = 0; c4 < 16; ++c4) {
      F4 p1;
      if (row0) p1.v = P14[base4 + (c4g0 + c4) * 128 + jm1];
      else      p1.v = *(const float4*)&p1e[r][(c4g0 + c4) * 4];
#pragma unroll
      for (int e = 0; e < 4; ++e) {
        const float u = pp[c4].f[e] + p1.f[e];
        psum += u;
        psq = fmaf(u, u, psq);
      }
    }
    red1[q][jl] = psum;
    red2[q][jl] = psq;
    __syncthreads();
    const float tsum = red1[0][jl] + red1[1][jl] + red1[2][jl] + red1[3][jl];
    const float tsq  = red2[0][jl] + red2[1][jl] + red2[2][jl] + red2[3][jl];
    const float mean = tsum * (1.f / 256.f);
    const float var  = tsq * (1.f / 256.f) - mean * mean;
    const float rstd = 1.f / sqrtf(var + LN_EPS);
    const float mA = rstd;
    const float mB = -mean * rstd;

    // relu(LN(u)) dot v2 over my 64 channels
    float acc[8];
#pragma unroll
    for (int h = 0; h < 8; ++h) acc[h] = 0.f;
#pragma unroll
    for (int c4 = 0; c4 < 16; ++c4) {
      F4 p1;
      if (row0) p1.v = P14[base4 + (c4g0 + c4) * 128 + jm1];
      else      p1.v = *(const float4*)&p1e[r][(c4g0 + c4) * 4];
      F4 g4; g4.v = *(const float4*)&ln_g[(c4g0 + c4) * 4];
      F4 b4; b4.v = *(const float4*)&ln_b[(c4g0 + c4) * 4];
      float w4[4];
#pragma unroll
      for (int e = 0; e < 4; ++e) {
        const float u = pp[c4].f[e] + p1.f[e];
        const float zt = fmaf(u, mA, mB);
        w4[e] = fmaxf(fmaf(zt, g4.f[e], b4.f[e]), 0.f);
      }
#pragma unroll
      for (int h = 0; h < 8; ++h) {
        F4 v2v; v2v.v = *(const float4*)&v2p[h * D + (c4g0 + c4) * 4];
        float d0 = fmaf(w4[0], v2v.f[0], acc[h]);
        float d1 = fmaf(w4[1], v2v.f[1], d0);
        float d2 = fmaf(w4[2], v2v.f[2], d1);
        acc[h] = fmaf(w4[3], v2v.f[3], d2);
      }
    }
#pragma unroll
    for (int h = 0; h < 8; ++h) dsh[q][jl][h] = acc[h];
    __syncthreads();

    // scores for heads {q, q+4}; softmax over jl (waves w and w^1)
    const bool masked = (jl == 0) || (jl == irow);
    float sc[2], pr[2];
#pragma unroll
    for (int hh = 0; hh < 2; ++hh) {
      const int h = q + hh * 4;
      const float v = aqs[r][h] + akr[hh]
                      + dsh[0][jl][h] + dsh[1][jl][h]
                      + dsh[2][jl][h] + dsh[3][jl][h];
      sc[hh] = masked ? -INFINITY : v;
    }
    float mx[2];
#pragma unroll
    for (int hh = 0; hh < 2; ++hh) {
      float v = sc[hh];
#pragma unroll
      for (int o = 1; o < 64; o <<= 1) v = fmaxf(v, __shfl_xor(v, o));
      mx[hh] = v;
    }
    if ((t & 63) == 0) { redm[w][0] = mx[0]; redm[w][1] = mx[1]; }
    __syncthreads();
#pragma unroll
    for (int hh = 0; hh < 2; ++hh) {
      const float m = fmaxf(redm[w][hh], redm[w ^ 1][hh]);
      pr[hh] = expf(sc[hh] - m);
    }
    float sm[2];
#pragma unroll
    for (int hh = 0; hh < 2; ++hh) {
      float v = pr[hh];
#pragma unroll
      for (int o = 1; o < 64; o <<= 1) v += __shfl_xor(v, o);
      sm[hh] = v;
    }
    if ((t & 63) == 0) { reds[w][0] = sm[0]; reds[w][1] = sm[1]; }
    __syncthreads();
#pragma unroll
    for (int hh = 0; hh < 2; ++hh) {
      const float at = pr[hh] / (reds[w][hh] + reds[w ^ 1][hh]);
      attnp[((b * H + q + hh * 4) * N + irow) * N + jl] = at;
    }
  }
}

// K5: ctx = attn @ v ; out = ctx @ wo + bo. 4 rows per block, 1024 threads
// (r = t>>8 row, c = t&255 channel). grid 256 (XCD-swizzled).
__global__ __launch_bounds__(1024, 4) void k5_out(
    const float* __restrict__ ws, const float* __restrict__ attnp,
    const float* __restrict__ wo, const float* __restrict__ bo,
    float* __restrict__ outp) {
  const int bid = blockIdx.x;
  const int wg = (bid & 7) * 32 + (bid >> 3);   // bijective; same-b per XCD
  const int b = wg >> 5;
  const int i0 = (wg & 31) * 4;
  const int t = threadIdx.x;
  const int r = t >> 8, c = t & 255;

  __shared__ float attn_sh[4][H][N];
  __shared__ float ctxs[4][260];

  for (int k = t; k < 4 * H * N; k += 1024) {
    const int rr = k >> 10, h = (k >> 7) & 7, j = k & 127;
    attn_sh[rr][h][j] = attnp[((b * H + h) * N + i0 + rr) * N + j];
  }
  __syncthreads();

  const int hh = c >> 5;
  const float* Vb = ws + WS_V + b * N * D + c;
  float acc = 0.f;
  for (int j = 0; j < N; ++j)
    acc = fmaf(attn_sh[r][hh][j], Vb[j * D], acc);
  ctxs[r][c] = acc;
  __syncthreads();

  float o = bo[c];
  for (int c2 = 0; c2 < D; c2 += 4) {
    F4 cx; cx.v = *(const float4*)&ctxs[r][c2];
    o = fmaf(cx.f[0], wo[(c2 + 0) * D + c], o);
    o = fmaf(cx.f[1], wo[(c2 + 1) * D + c], o);
    o = fmaf(cx.f[2], wo[(c2 + 2) * D + c], o);
    o = fmaf(cx.f[3], wo[(c2 + 3) * D + c], o);
  }
  outp[(b * N + i0 + r) * D + c] = o;
}

extern "C" void kernel_launch(void* const* d_in, const int* in_sizes, int n_in,
                              void* d_out, int out_size, void* d_ws, size_t ws_size,
                              hipStream_t stream) {
  (void)in_sizes; (void)n_in; (void)out_size; (void)ws_size;
  const float* desc = (const float*)d_in[0];
  const float* nv   = (const float*)d_in[1];
  const float* wq   = (const float*)d_in[2];
  const float* bq   = (const float*)d_in[3];
  const float* wk   = (const float*)d_in[4];
  const float* bk   = (const float*)d_in[5];
  const float* wv   = (const float*)d_in[6];
  const float* bv   = (const float*)d_in[7];
  const float* ew1  = (const float*)d_in[8];
  const float* eb1  = (const float*)d_in[9];
  const float* ln_g = (const float*)d_in[10];
  const float* ln_b = (const float*)d_in[11];
  const float* ew2  = (const float*)d_in[12];
  const float* eb2  = (const float*)d_in[13];
  const float* aw   = (const float*)d_in[14];
  const float* ab   = (const float*)d_in[15];
  const float* wo   = (const float*)d_in[16];
  const float* bo   = (const float*)d_in[17];

  float* ws   = (float*)d_ws;
  float* outp = (float*)d_out;
  float* attnp = outp + B * N * D;

  k1_fold<<<25, 256, 0, stream>>>(wq, wk, ew2, bq, bk, eb2, aw, ws);
  kA_pre<<<512, 256, 0, stream>>>(desc, ew1, eb1, nv, wv, bv, ws);
  k4_attn<<<512, 512, 0, stream>>>(ws, ln_g, ln_b, ab, attnp);
  k5_out<<<256, 1024, 0, stream>>>(ws, attnp, wo, bo, outp);
}

// Round 5
// 90.568 us; speedup vs baseline: 6.3832x; 6.3832x over previous
//
#include <hip/hip_runtime.h>
#include <math.h>

namespace {
constexpr int D = 256;
constexpr int H = 8;
constexpr int HD = 32;
constexpr int B = 8;
constexpr int S = 127;
constexpr int N = 128;
constexpr float LN_EPS = 1e-5f;

// ws layout (float offsets). P1T/P2T are stored PACKED:
// element (b, c, i) at (b*64 + (c>>2))*512 + i*4 + (c&3)  -> float4 over c for fixed i.
// P1T rows INCLUDE eb1 (folded at kA time).
constexpr int WS_P1T = 0;                  // B*D*N
constexpr int WS_P2T = WS_P1T + B * D * N; // B*D*N
constexpr int WS_V   = WS_P2T + B * D * N; // B*N*D (row-major)
constexpr int WS_AQ  = WS_V + B * N * D;   // B*H*N
constexpr int WS_AK  = WS_AQ + B * H * N;  // B*H*N
constexpr int WS_FQK = WS_AK + B * H * N;  // D*16 (wq-fold | wk-fold)
constexpr int WS_V2  = WS_FQK + D * 16;    // H*D (transposed: [h][c])
constexpr int WS_BF  = WS_V2 + D * H;      // 32 (bq-fold[8], bk-fold[8], be-fold[8])
constexpr int WS_ST  = WS_BF + 32;         // B*4*N row stats: S1,Q1,S2,Q2 (incl eb1 in P1)

union F4 { float4 v; float f[4]; };
} // namespace

// K1: fold wq/wk with attn_w[:32]/[32:64] -> FQK (D x 16), ew2 with attn_w[64:96]
// -> V2T (H x D), plus bias folds. Thread-per-output.
__global__ __launch_bounds__(256) void k1_fold(
    const float* __restrict__ wq, const float* __restrict__ wk,
    const float* __restrict__ ew2, const float* __restrict__ bq,
    const float* __restrict__ bk, const float* __restrict__ eb2,
    const float* __restrict__ attn_w, float* __restrict__ ws) {
  float* FQK = ws + WS_FQK;
  float* V2T = ws + WS_V2;
  float* BF  = ws + WS_BF;
  const int tg = blockIdx.x * 256 + threadIdx.x;
  if (tg < 6144) {
    const int mat = tg >> 11;
    const int rem = tg & 2047;
    const int c = rem >> 3;
    const int h = rem & 7;
    const float* W = (mat == 0) ? wq : (mat == 1) ? wk : ew2;
    const float* aw = attn_w + mat * HD;
    const float* wrow = W + c * D + h * HD;
    float s = 0.f;
#pragma unroll
    for (int d = 0; d < HD; ++d) s = fmaf(wrow[d], aw[d], s);
    if (mat < 2) FQK[c * 16 + mat * 8 + h] = s;
    else         V2T[h * D + c] = s;
  } else if (tg < 6168) {
    const int idx = tg - 6144;
    const int mat = idx >> 3;
    const int h = idx & 7;
    const float* bias = (mat == 0) ? bq : (mat == 1) ? bk : eb2;
    const float* aw = attn_w + mat * HD;
    float s = 0.f;
#pragma unroll
    for (int d = 0; d < HD; ++d) s = fmaf(bias[h * HD + d], aw[d], s);
    BF[mat * 8 + h] = s;
  }
}

// KA: role 0 (blocks 0..255): P1/P2 packed-transposed (+eb1 into P1) and the
// per-row stats S1,Q1,S2,Q2. role 1 (blocks 256..511): V rows + aq/ak.
__global__ __launch_bounds__(256) void kA_pre(
    const float* __restrict__ desc, const float* __restrict__ ew1,
    const float* __restrict__ eb1,
    const float* __restrict__ nv, const float* __restrict__ wv,
    const float* __restrict__ bv, float* __restrict__ ws) {
  const int blk = blockIdx.x;
  const int t = threadIdx.x;
  __shared__ float rows[4][264];
  __shared__ float aqred[4][64];
  __shared__ float statred[4][16];

  if (blk < 256) {
    // ---- role 0 ----
    float* P1Tf = ws + WS_P1T;
    float* P2Tf = ws + WS_P2T;
    const int b = blk >> 5;
    const int i0 = (blk & 31) * 4;
    for (int k = t; k < 4 * D; k += 256) {
      const int r = k >> 8, c = k & (D - 1);
      const int row = i0 + r;
      rows[r][c] = (row < S) ? desc[(b * S + row) * D + c] : 0.f;
    }
    __syncthreads();
    float a1[4], a2[4];
#pragma unroll
    for (int ii = 0; ii < 4; ++ii) { a1[ii] = 0.f; a2[ii] = 0.f; }
    for (int c2 = 0; c2 < D; c2 += 4) {
      float w1[4], w2[4];
#pragma unroll
      for (int e = 0; e < 4; ++e) {
        w1[e] = ew1[(c2 + e) * D + t];
        w2[e] = ew1[(D + c2 + e) * D + t];
      }
#pragma unroll
      for (int ii = 0; ii < 4; ++ii) {
        F4 dv; dv.v = *(const float4*)&rows[ii][c2];
#pragma unroll
        for (int e = 0; e < 4; ++e) {
          a1[ii] = fmaf(dv.f[e], w1[e], a1[ii]);
          a2[ii] = fmaf(dv.f[e], w2[e], a2[ii]);
        }
      }
    }
    const float ebv = eb1[t];
    const int pbase = (b * 64 + (t >> 2)) * 512 + (t & 3);
#pragma unroll
    for (int ii = 0; ii < 4; ++ii) {
      if (i0 + ii < S) {
        P1Tf[pbase + (i0 + ii) * 4] = a1[ii] + ebv;
        P2Tf[pbase + (i0 + ii) * 4] = a2[ii];
      }
    }
    // per-row stats (S1,Q1 of p1+eb1; S2,Q2 of p2), reduced over channels
    float stv[16];
#pragma unroll
    for (int ii = 0; ii < 4; ++ii) {
      const float v1 = a1[ii] + ebv;
      const float v2x = a2[ii];
      stv[ii * 4 + 0] = v1;
      stv[ii * 4 + 1] = v1 * v1;
      stv[ii * 4 + 2] = v2x;
      stv[ii * 4 + 3] = v2x * v2x;
    }
#pragma unroll
    for (int st = 0; st < 16; ++st) {
#pragma unroll
      for (int o = 1; o < 64; o <<= 1) stv[st] += __shfl_xor(stv[st], o);
    }
    const int w = t >> 6;
    if ((t & 63) == 0) {
#pragma unroll
      for (int st = 0; st < 16; ++st) statred[w][st] = stv[st];
    }
    __syncthreads();
    if (t < 16) {
      const int ii = t >> 2, st = t & 3;
      if (i0 + ii < S) {
        const float s = statred[0][t] + statred[1][t]
                      + statred[2][t] + statred[3][t];
        ws[WS_ST + b * 512 + st * 128 + (i0 + ii)] = s;
      }
    }
  } else {
    // ---- role 1: v = nv @ wv + bv, aq/ak via folded FQK ----
    float* Vf  = ws + WS_V;
    float* AQ  = ws + WS_AQ;
    float* AK  = ws + WS_AK;
    const float* FQK = ws + WS_FQK;
    const float* BF  = ws + WS_BF;
    const int blk2 = blk - 256;
    const int b = blk2 >> 5;
    const int j0 = (blk2 & 31) * 4;
    for (int k = t; k < 4 * D; k += 256) {
      const int r = k >> 8, c = k & (D - 1);
      rows[r][c] = nv[(b * N + j0 + r) * D + c];
    }
    __syncthreads();
    float acc[4];
#pragma unroll
    for (int jj = 0; jj < 4; ++jj) acc[jj] = 0.f;
    for (int c2 = 0; c2 < D; c2 += 4) {
      float wvv[4];
#pragma unroll
      for (int e = 0; e < 4; ++e) wvv[e] = wv[(c2 + e) * D + t];
#pragma unroll
      for (int jj = 0; jj < 4; ++jj) {
        F4 x; x.v = *(const float4*)&rows[jj][c2];
#pragma unroll
        for (int e = 0; e < 4; ++e) acc[jj] = fmaf(x.f[e], wvv[e], acc[jj]);
      }
    }
    const float bias = bv[t];
#pragma unroll
    for (int jj = 0; jj < 4; ++jj)
      Vf[(b * N + j0 + jj) * D + t] = acc[jj] + bias;

    const int pair = t & 63;        // (row il, output oi)
    const int cq = t >> 6;          // channel quarter
    const int il = pair >> 4, oi = pair & 15;
    float s = 0.f;
    for (int c = cq * 64; c < cq * 64 + 64; ++c)
      s = fmaf(rows[il][c], FQK[c * 16 + oi], s);
    aqred[cq][pair] = s;
    __syncthreads();
    if (t < 64) {
      const int il2 = t >> 4, oi2 = t & 15;
      float s2 = aqred[0][t] + aqred[1][t] + aqred[2][t] + aqred[3][t] + BF[oi2];
      if (oi2 < 8) AQ[(b * H + oi2) * N + j0 + il2] = s2;
      else         AK[(b * H + (oi2 - 8)) * N + j0 + il2] = s2;
    }
  }
}

// K4: edge-MLP -> scores -> softmax -> attn write.
// grid 512 (XCD-swizzled): block = (b, 2-row i-tile). 512 threads:
// jl = t&127 (column j), q = t>>7: rp = q&1 (row), hg = q>>1 (channel half).
// LN stats come from precomputed row sums + a G = p1.p2 dot (loop A);
// loop B computes relu(LN(u)) . v2 for all 8 heads over hg's 128 channels.
// No register slab caching, no launch_bounds occupancy arg (spill-safe).
__global__ __launch_bounds__(512) void k4_attn(
    const float* __restrict__ ws,
    const float* __restrict__ ln_g, const float* __restrict__ ln_b,
    const float* __restrict__ attn_bp, float* __restrict__ attnp) {
  const int bid = blockIdx.x;
  const int wg = (bid & 7) * 64 + (bid >> 3);   // bijective; one b per XCD
  const int b = wg >> 6;
  const int i0 = (wg & 63) * 2;
  const int t = threadIdx.x;
  const int jl = t & 127;
  const int q = t >> 7;
  const int rp = q & 1;
  const int hg = q >> 1;

  __shared__ float p1e[2][D];
  __shared__ float aqs[2][8];
  __shared__ float gpart[2][2][128];
  __shared__ float dpart[2][2][128][8];
  __shared__ float redm[8][4], reds[8][4];

  const float* P1Tf = ws + WS_P1T;
  const float* AQ   = ws + WS_AQ;
  const float* AK   = ws + WS_AK;
  const float* BF   = ws + WS_BF;
  const float* v2p  = ws + WS_V2;
  const float* ST   = ws + WS_ST + b * 512;

  for (int k = t; k < 2 * D; k += 512) {
    const int r = k >> 8, c = k & 255;
    const int idx = i0 + r - 1;
    p1e[r][c] = (idx >= 0)
        ? P1Tf[(b * 64 + (c >> 2)) * 512 + idx * 4 + (c & 3)] : 0.f;
  }
  if (t < 16) {
    const int r = t >> 3, h = t & 7;
    aqs[r][h] = AQ[(b * H + h) * N + i0 + r] + BF[16 + h] + attn_bp[0];
  }
  __syncthreads();

  const int jm1 = (jl == 0) ? 0 : jl - 1;
  const int irow = i0 + rp;
  const bool row0 = (irow == 0);   // row i==0 uses per-lane P1[j-1]
  const float4* P14 = reinterpret_cast<const float4*>(ws + WS_P1T);
  const float4* P24 = reinterpret_cast<const float4*>(ws + WS_P2T);
  const int base4 = b * 64 * 128;
  const int c40 = hg * 32;

  // ---- loop A: G = sum_c p1[c]*p2[c] over my 32 c4-groups ----
  float g = 0.f;
  for (int cc = 0; cc < 32; ++cc) {
    const int c4 = c40 + cc;
    F4 p2; p2.v = P24[base4 + c4 * 128 + jm1];
    F4 p1;
    if (row0) p1.v = P14[base4 + c4 * 128 + jm1];
    else      p1.v = *(const float4*)&p1e[rp][c4 * 4];
    g = fmaf(p1.f[0], p2.f[0], g);
    g = fmaf(p1.f[1], p2.f[1], g);
    g = fmaf(p1.f[2], p2.f[2], g);
    g = fmaf(p1.f[3], p2.f[3], g);
  }
  gpart[hg][rp][jl] = g;
  __syncthreads();
  const float G  = gpart[0][rp][jl] + gpart[1][rp][jl];
  const float S1 = row0 ? ST[0 * 128 + jm1] : ST[0 * 128 + irow - 1];
  const float Q1 = row0 ? ST[1 * 128 + jm1] : ST[1 * 128 + irow - 1];
  const float S2 = ST[2 * 128 + jm1];
  const float Q2 = ST[3 * 128 + jm1];
  const float mean = (S1 + S2) * (1.f / 256.f);
  const float var  = (Q1 + Q2 + 2.f * G) * (1.f / 256.f) - mean * mean;
  const float rstd = 1.f / sqrtf(var + LN_EPS);
  const float mB = -mean * rstd;

  // ---- loop B: relu(LN(u)) . v2 for 8 heads over my 32 c4-groups ----
  float dt[8];
#pragma unroll
  for (int h = 0; h < 8; ++h) dt[h] = 0.f;
  for (int cc = 0; cc < 32; ++cc) {
    const int c4 = c40 + cc;
    F4 p2; p2.v = P24[base4 + c4 * 128 + jm1];
    F4 p1;
    if (row0) p1.v = P14[base4 + c4 * 128 + jm1];
    else      p1.v = *(const float4*)&p1e[rp][c4 * 4];
    F4 g4; g4.v = *(const float4*)&ln_g[c4 * 4];
    F4 b4; b4.v = *(const float4*)&ln_b[c4 * 4];
    float w4[4];
#pragma unroll
    for (int e = 0; e < 4; ++e) {
      const float u = p1.f[e] + p2.f[e];
      const float zt = fmaf(u, rstd, mB);
      w4[e] = fmaxf(fmaf(zt, g4.f[e], b4.f[e]), 0.f);
    }
#pragma unroll
    for (int h = 0; h < 8; ++h) {
      F4 v2v; v2v.v = *(const float4*)&v2p[h * D + c4 * 4];
      float d0 = fmaf(w4[0], v2v.f[0], dt[h]);
      float d1 = fmaf(w4[1], v2v.f[1], d0);
      float d2 = fmaf(w4[2], v2v.f[2], d1);
      dt[h] = fmaf(w4[3], v2v.f[3], d2);
    }
  }
  {
    F4 dlo, dhi;
#pragma unroll
    for (int e = 0; e < 4; ++e) { dlo.f[e] = dt[e]; dhi.f[e] = dt[4 + e]; }
    *(float4*)&dpart[hg][rp][jl][0] = dlo.v;
    *(float4*)&dpart[hg][rp][jl][4] = dhi.v;
  }
  __syncthreads();

  // ---- scores + softmax: thread q -> row rp, heads [hg*4, hg*4+4) ----
  const bool masked = (jl == 0) || (jl == irow);
  float sc[4], pr[4];
#pragma unroll
  for (int hh = 0; hh < 4; ++hh) {
    const int h = hg * 4 + hh;
    const float dsum = dpart[0][rp][jl][h] + dpart[1][rp][jl][h];
    const float v = aqs[rp][h] + AK[(b * H + h) * N + jl] + dsum;
    sc[hh] = masked ? -INFINITY : v;
  }
  const int w = t >> 6;   // softmax partner wave is w^1 (other jl-half)
  float mx[4];
#pragma unroll
  for (int hh = 0; hh < 4; ++hh) {
    float v = sc[hh];
#pragma unroll
    for (int o = 1; o < 64; o <<= 1) v = fmaxf(v, __shfl_xor(v, o));
    mx[hh] = v;
  }
  if ((t & 63) == 0) {
#pragma unroll
    for (int hh = 0; hh < 4; ++hh) redm[w][hh] = mx[hh];
  }
  __syncthreads();
#pragma unroll
  for (int hh = 0; hh < 4; ++hh) {
    const float m = fmaxf(redm[w][hh], redm[w ^ 1][hh]);
    pr[hh] = expf(sc[hh] - m);
  }
  float sm[4];
#pragma unroll
  for (int hh = 0; hh < 4; ++hh) {
    float v = pr[hh];
#pragma unroll
    for (int o = 1; o < 64; o <<= 1) v += __shfl_xor(v, o);
    sm[hh] = v;
  }
  if ((t & 63) == 0) {
#pragma unroll
    for (int hh = 0; hh < 4; ++hh) reds[w][hh] = sm[hh];
  }
  __syncthreads();
#pragma unroll
  for (int hh = 0; hh < 4; ++hh) {
    const float at = pr[hh] / (reds[w][hh] + reds[w ^ 1][hh]);
    attnp[((b * H + hg * 4 + hh) * N + irow) * N + jl] = at;
  }
}

// K5: ctx = attn @ v ; out = ctx @ wo + bo. 4 rows per block, 1024 threads
// (r = t>>8 row, c = t&255 channel). grid 256 (XCD-swizzled).
__global__ __launch_bounds__(1024) void k5_out(
    const float* __restrict__ ws, const float* __restrict__ attnp,
    const float* __restrict__ wo, const float* __restrict__ bo,
    float* __restrict__ outp) {
  const int bid = blockIdx.x;
  const int wg = (bid & 7) * 32 + (bid >> 3);   // bijective; same-b per XCD
  const int b = wg >> 5;
  const int i0 = (wg & 31) * 4;
  const int t = threadIdx.x;
  const int r = t >> 8, c = t & 255;

  __shared__ float attn_sh[4][H][N];
  __shared__ float ctxs[4][260];

  for (int k = t; k < 4 * H * N; k += 1024) {
    const int rr = k >> 10, h = (k >> 7) & 7, j = k & 127;
    attn_sh[rr][h][j] = attnp[((b * H + h) * N + i0 + rr) * N + j];
  }
  __syncthreads();

  const int hh = c >> 5;
  const float* Vb = ws + WS_V + b * N * D + c;
  float acc = 0.f;
  for (int j = 0; j < N; ++j)
    acc = fmaf(attn_sh[r][hh][j], Vb[j * D], acc);
  ctxs[r][c] = acc;
  __syncthreads();

  float o = bo[c];
  for (int c2 = 0; c2 < D; c2 += 4) {
    F4 cx; cx.v = *(const float4*)&ctxs[r][c2];
    o = fmaf(cx.f[0], wo[(c2 + 0) * D + c], o);
    o = fmaf(cx.f[1], wo[(c2 + 1) * D + c], o);
    o = fmaf(cx.f[2], wo[(c2 + 2) * D + c], o);
    o = fmaf(cx.f[3], wo[(c2 + 3) * D + c], o);
  }
  outp[(b * N + i0 + r) * D + c] = o;
}

extern "C" void kernel_launch(void* const* d_in, const int* in_sizes, int n_in,
                              void* d_out, int out_size, void* d_ws, size_t ws_size,
                              hipStream_t stream) {
  (void)in_sizes; (void)n_in; (void)out_size; (void)ws_size;
  const float* desc = (const float*)d_in[0];
  const float* nv   = (const float*)d_in[1];
  const float* wq   = (const float*)d_in[2];
  const float* bq   = (const float*)d_in[3];
  const float* wk   = (const float*)d_in[4];
  const float* bk   = (const float*)d_in[5];
  const float* wv   = (const float*)d_in[6];
  const float* bv   = (const float*)d_in[7];
  const float* ew1  = (const float*)d_in[8];
  const float* eb1  = (const float*)d_in[9];
  const float* ln_g = (const float*)d_in[10];
  const float* ln_b = (const float*)d_in[11];
  const float* ew2  = (const float*)d_in[12];
  const float* eb2  = (const float*)d_in[13];
  const float* aw   = (const float*)d_in[14];
  const float* ab   = (const float*)d_in[15];
  const float* wo   = (const float*)d_in[16];
  const float* bo   = (const float*)d_in[17];

  float* ws   = (float*)d_ws;
  float* outp = (float*)d_out;
  float* attnp = outp + B * N * D;

  k1_fold<<<25, 256, 0, stream>>>(wq, wk, ew2, bq, bk, eb2, aw, ws);
  kA_pre<<<512, 256, 0, stream>>>(desc, ew1, eb1, nv, wv, bv, ws);
  k4_attn<<<512, 512, 0, stream>>>(ws, ln_g, ln_b, ab, attnp);
  k5_out<<<256, 1024, 0, stream>>>(ws, attnp, wo, bo, outp);
}